// Round 1
// baseline (542.111 us; speedup 1.0000x reference)
//
#include <hip/hip_runtime.h>
#include <hip/hip_bf16.h>
#include <stdint.h>

static constexpr int N_ = 16384;
static constexpr int D_ = 2048;
static constexpr float SCALE_R = 1.0f / 16.0f;            // 1/sqrt(HD=256)
static constexpr float SCALE_W = 0.02209708691207961f;    // 1/sqrt(D=2048)

typedef __bf16 bf16x8 __attribute__((ext_vector_type(8)));
typedef float f32x4 __attribute__((ext_vector_type(4)));

__device__ __forceinline__ unsigned short f2bf(float f) {
  unsigned int u = __float_as_uint(f);
  unsigned int r = (u + 0x7fff + ((u >> 16) & 1)) >> 16;  // RNE
  return (unsigned short)r;
}

__device__ __forceinline__ void lds_load16(void* lds, const void* g) {
  __builtin_amdgcn_global_load_lds(
      (const __attribute__((address_space(1))) uint32_t*)(uintptr_t)g,
      (__attribute__((address_space(3))) uint32_t*)(uint32_t)(uintptr_t)lds,
      16, 0, 0);
}

// ---- K1: k = memory@Wrk.T, v = memory@Wrv.T, wq = memory@Wwq.T  (each [8][2048])
__global__ __launch_bounds__(256) void k_kvwq(
    const float* __restrict__ mem, const float* __restrict__ wrk,
    const float* __restrict__ wrv, const float* __restrict__ wwq,
    float* __restrict__ kbuf, float* __restrict__ vbuf, float* __restrict__ wqbuf) {
  int gw = (blockIdx.x * 256 + threadIdx.x) >> 6;  // 0..6143
  int lane = threadIdx.x & 63;
  int which = gw >> 11;
  int j = gw & 2047;
  const float* W = which == 0 ? wrk : (which == 1 ? wrv : wwq);
  float* O = which == 0 ? kbuf : (which == 1 ? vbuf : wqbuf);
  const f32x4* Wrow = (const f32x4*)(W + (size_t)j * D_);
  const f32x4* M4 = (const f32x4*)mem;
  float acc[8];
#pragma unroll
  for (int kk = 0; kk < 8; ++kk) acc[kk] = 0.f;
#pragma unroll
  for (int t = 0; t < 8; ++t) {
    f32x4 w4 = Wrow[lane + 64 * t];
#pragma unroll
    for (int kk = 0; kk < 8; ++kk) {
      f32x4 m4 = M4[kk * 512 + lane + 64 * t];
      acc[kk] += w4[0] * m4[0] + w4[1] * m4[1] + w4[2] * m4[2] + w4[3] * m4[3];
    }
  }
#pragma unroll
  for (int off = 1; off < 64; off <<= 1)
#pragma unroll
    for (int kk = 0; kk < 8; ++kk) acc[kk] += __shfl_xor(acc[kk], off, 64);
  if (lane == 0) {
#pragma unroll
    for (int kk = 0; kk < 8; ++kk) O[kk * D_ + j] = acc[kk];
  }
}

// ---- K2: PRT[80][2048]: rows 0..63 = P (scaled 1/16), rows 64..71 = R (scaled 1/sqrt(D))
__global__ __launch_bounds__(256) void k_pr(
    const float* __restrict__ wrq, const float* __restrict__ wwk,
    const float* __restrict__ kbuf, const float* __restrict__ wqbuf,
    float* __restrict__ PRT) {
  int b = blockIdx.x;
  int tid = threadIdx.x;
  if (b < 64) {
    int ic = b >> 3, h = b & 7;
    int i = ic * 256 + tid;
    float acc[8];
#pragma unroll
    for (int kk = 0; kk < 8; ++kk) acc[kk] = 0.f;
    for (int jj = 0; jj < 256; ++jj) {
      int j = h * 256 + jj;
      float wv = wrq[(size_t)j * D_ + i];
#pragma unroll
      for (int kk = 0; kk < 8; ++kk) acc[kk] += wv * kbuf[kk * D_ + j];
    }
#pragma unroll
    for (int kk = 0; kk < 8; ++kk) PRT[(h * 8 + kk) * D_ + i] = acc[kk] * SCALE_R;
  } else {
    int bb = b - 64;
    int ic = bb >> 3, jc = bb & 7;
    int i = ic * 256 + tid;
    float acc[8];
#pragma unroll
    for (int kk = 0; kk < 8; ++kk) acc[kk] = 0.f;
    for (int jj = 0; jj < 256; ++jj) {
      int j = jc * 256 + jj;
      float wv = wwk[(size_t)j * D_ + i];
#pragma unroll
      for (int kk = 0; kk < 8; ++kk) acc[kk] += wv * wqbuf[kk * D_ + j];
    }
#pragma unroll
    for (int kk = 0; kk < 8; ++kk) atomicAdd(&PRT[(64 + kk) * D_ + i], acc[kk] * SCALE_W);
  }
}

// ---- convert fp32 -> bf16 (for Wout)
__global__ __launch_bounds__(256) void k_cvt(const float* __restrict__ src,
                                             unsigned short* __restrict__ dst, int n4) {
  int i = blockIdx.x * 256 + threadIdx.x;
  if (i >= n4) return;
  f32x4 v = ((const f32x4*)src)[i];
  ushort4 o;
  o.x = f2bf(v[0]); o.y = f2bf(v[1]); o.z = f2bf(v[2]); o.w = f2bf(v[3]);
  ((ushort4*)dst)[i] = o;
}

// ---- K3: main fused pass over hidden rows:
//   S[64 rows][80] = hidden_chunk @ PRT^T  (fp32 LDS-tiled)
//   -> read-softmax (per head, 8 slots) -> read_out -> LN -> Xhat (bf16)
//   -> e8 = exp(s_w) -> block-partial u = sum_n e8*hidden, Z = sum_n e8
__global__ __launch_bounds__(256) void k_main(
    const float* __restrict__ hidden, const float* __restrict__ PRT,
    const float* __restrict__ vbuf, const float* __restrict__ gamma,
    const float* __restrict__ beta, unsigned short* __restrict__ Xhat,
    float* __restrict__ upart, float* __restrict__ Zpart) {
  __shared__ float Ah[64][65];
  __shared__ float Bh[80][65];
  __shared__ float Slds[64][81];
  __shared__ float vlds[8 * 2048];
  __shared__ float e8lds[64][8];
  const int tid = threadIdx.x;
  const int row0 = blockIdx.x * 64;
  const int ty = tid >> 4, tx = tid & 15;
  const int wave = tid >> 6, lane = tid & 63;

  float acc[4][5];
#pragma unroll
  for (int i = 0; i < 4; ++i)
#pragma unroll
    for (int j = 0; j < 5; ++j) acc[i][j] = 0.f;

  const int srow = tid >> 4;        // 0..15
  const int scol = (tid & 15) * 4;  // 0..60

  for (int kt = 0; kt < 32; ++kt) {
    const int k0 = kt * 64;
#pragma unroll
    for (int p = 0; p < 4; ++p) {
      int r = srow + p * 16;
      f32x4 v = *(const f32x4*)(hidden + (size_t)(row0 + r) * D_ + k0 + scol);
      Ah[r][scol] = v[0]; Ah[r][scol + 1] = v[1]; Ah[r][scol + 2] = v[2]; Ah[r][scol + 3] = v[3];
    }
#pragma unroll
    for (int p = 0; p < 5; ++p) {
      int c = srow + p * 16;
      f32x4 v = *(const f32x4*)(PRT + (size_t)c * D_ + k0 + scol);
      Bh[c][scol] = v[0]; Bh[c][scol + 1] = v[1]; Bh[c][scol + 2] = v[2]; Bh[c][scol + 3] = v[3];
    }
    __syncthreads();
#pragma unroll 8
    for (int k = 0; k < 64; ++k) {
      float a0 = Ah[ty * 4 + 0][k], a1 = Ah[ty * 4 + 1][k];
      float a2 = Ah[ty * 4 + 2][k], a3 = Ah[ty * 4 + 3][k];
      float b0 = Bh[tx * 5 + 0][k], b1 = Bh[tx * 5 + 1][k], b2 = Bh[tx * 5 + 2][k];
      float b3 = Bh[tx * 5 + 3][k], b4 = Bh[tx * 5 + 4][k];
      acc[0][0] += a0 * b0; acc[0][1] += a0 * b1; acc[0][2] += a0 * b2; acc[0][3] += a0 * b3; acc[0][4] += a0 * b4;
      acc[1][0] += a1 * b0; acc[1][1] += a1 * b1; acc[1][2] += a1 * b2; acc[1][3] += a1 * b3; acc[1][4] += a1 * b4;
      acc[2][0] += a2 * b0; acc[2][1] += a2 * b1; acc[2][2] += a2 * b2; acc[2][3] += a2 * b3; acc[2][4] += a2 * b4;
      acc[3][0] += a3 * b0; acc[3][1] += a3 * b1; acc[3][2] += a3 * b2; acc[3][3] += a3 * b3; acc[3][4] += a3 * b4;
    }
    __syncthreads();
  }

  // scatter S to LDS; stage v into LDS
#pragma unroll
  for (int i = 0; i < 4; ++i)
#pragma unroll
    for (int j = 0; j < 5; ++j) Slds[ty * 4 + i][tx * 5 + j] = acc[i][j];
#pragma unroll
  for (int p = 0; p < 16; ++p) {
    int lin = p * 256 + tid;
    f32x4 v = ((const f32x4*)vbuf)[lin];
    *(f32x4*)&vlds[lin * 4] = v;
  }
  __syncthreads();

  for (int rr = 0; rr < 16; ++rr) {
    const int ln = wave * 16 + rr;
    const int gn = row0 + ln;
    // per-head softmax over 8 slots (lane c = h*8+kk)
    float s = Slds[ln][lane];
    float m = s;
    m = fmaxf(m, __shfl_xor(m, 1, 64));
    m = fmaxf(m, __shfl_xor(m, 2, 64));
    m = fmaxf(m, __shfl_xor(m, 4, 64));
    float e = __expf(s - m);
    float ssum = e;
    ssum += __shfl_xor(ssum, 1, 64);
    ssum += __shfl_xor(ssum, 2, 64);
    ssum += __shfl_xor(ssum, 4, 64);
    float a = e / ssum;
    if (lane < 8) e8lds[ln][lane] = __expf(Slds[ln][64 + lane]);

    float ro_reg[32];
    float sum = 0.f, sumsq = 0.f;
#pragma unroll
    for (int h = 0; h < 8; ++h) {
      float av0 = __shfl(a, h * 8 + 0, 64), av1 = __shfl(a, h * 8 + 1, 64);
      float av2 = __shfl(a, h * 8 + 2, 64), av3 = __shfl(a, h * 8 + 3, 64);
      float av4 = __shfl(a, h * 8 + 4, 64), av5 = __shfl(a, h * 8 + 5, 64);
      float av6 = __shfl(a, h * 8 + 6, 64), av7 = __shfl(a, h * 8 + 7, 64);
#pragma unroll
      for (int t4 = 0; t4 < 4; ++t4) {
        int t = h * 4 + t4;
        int d = t * 64 + lane;
        float ro = av0 * vlds[0 * 2048 + d] + av1 * vlds[1 * 2048 + d] +
                   av2 * vlds[2 * 2048 + d] + av3 * vlds[3 * 2048 + d] +
                   av4 * vlds[4 * 2048 + d] + av5 * vlds[5 * 2048 + d] +
                   av6 * vlds[6 * 2048 + d] + av7 * vlds[7 * 2048 + d];
        ro_reg[t] = ro;
        sum += ro; sumsq += ro * ro;
      }
    }
#pragma unroll
    for (int off = 1; off < 64; off <<= 1) {
      sum += __shfl_xor(sum, off, 64);
      sumsq += __shfl_xor(sumsq, off, 64);
    }
    float mu = sum * (1.f / 2048.f);
    float var = sumsq * (1.f / 2048.f) - mu * mu;
    float rstd = rsqrtf(var + 1e-5f);
#pragma unroll
    for (int t = 0; t < 32; ++t) {
      int d = t * 64 + lane;
      float xh = (ro_reg[t] - mu) * rstd * gamma[d] + beta[d];
      Xhat[(size_t)gn * D_ + d] = f2bf(xh);
    }
  }
  __syncthreads();

  // u-partial: wave owns 512-wide d-range
  for (int dt = 0; dt < 8; ++dt) {
    int d = wave * 512 + dt * 64 + lane;
    float ua[8];
#pragma unroll
    for (int kk = 0; kk < 8; ++kk) ua[kk] = 0.f;
    for (int ln = 0; ln < 64; ++ln) {
      float hv = hidden[(size_t)(row0 + ln) * D_ + d];
#pragma unroll
      for (int kk = 0; kk < 8; ++kk) ua[kk] += e8lds[ln][kk] * hv;
    }
#pragma unroll
    for (int kk = 0; kk < 8; ++kk)
      upart[((size_t)blockIdx.x * 8 + kk) * 2048 + d] = ua[kk];
  }
  if (tid < 8) {
    float z = 0.f;
    for (int ln = 0; ln < 64; ++ln) z += e8lds[ln][tid];
    Zpart[blockIdx.x * 8 + tid] = z;
  }
}

// ---- K4: reduce u-partials, t = u/Z  ([8][2048])
__global__ __launch_bounds__(256) void k_ured(const float* __restrict__ upart,
                                              const float* __restrict__ Zpart,
                                              float* __restrict__ tbuf) {
  int g = blockIdx.x * 256 + threadIdx.x;  // 0..16383
  int kk = g >> 11, d = g & 2047;
  float z = 0.f;
  for (int b = 0; b < 256; ++b) z += Zpart[b * 8 + kk];
  float u = 0.f;
  for (int b = 0; b < 256; ++b) u += upart[((size_t)b * 8 + kk) * 2048 + d];
  tbuf[g] = u / z;
}

// ---- K5b: new_memory = (1-wg)*memory + wg * (t @ Wwv.T)
__global__ __launch_bounds__(256) void k_newmem(
    const float* __restrict__ tbuf, const float* __restrict__ wwv,
    const float* __restrict__ mem, const float* __restrict__ wgate,
    float* __restrict__ out_mem) {
  int j = (blockIdx.x * 256 + threadIdx.x) >> 6;  // 0..2047
  int lane = threadIdx.x & 63;
  const f32x4* Wrow = (const f32x4*)(wwv + (size_t)j * D_);
  const f32x4* T4 = (const f32x4*)tbuf;
  float acc[8];
#pragma unroll
  for (int kk = 0; kk < 8; ++kk) acc[kk] = 0.f;
#pragma unroll
  for (int t = 0; t < 8; ++t) {
    f32x4 w4 = Wrow[lane + 64 * t];
#pragma unroll
    for (int kk = 0; kk < 8; ++kk) {
      f32x4 t4 = T4[kk * 512 + lane + 64 * t];
      acc[kk] += w4[0] * t4[0] + w4[1] * t4[1] + w4[2] * t4[2] + w4[3] * t4[3];
    }
  }
#pragma unroll
  for (int off = 1; off < 64; off <<= 1)
#pragma unroll
    for (int kk = 0; kk < 8; ++kk) acc[kk] += __shfl_xor(acc[kk], off, 64);
  if (lane == 0) {
    float wg = 1.f / (1.f + __expf(-wgate[0]));
#pragma unroll
    for (int kk = 0; kk < 8; ++kk)
      out_mem[kk * D_ + j] = (1.f - wg) * mem[kk * D_ + j] + wg * acc[kk];
  }
}

// ---- K5: result = hidden + g * (Xhat @ Wout.T)   bf16 MFMA, 128x128 tile
__global__ __launch_bounds__(256) void k_gemm(
    const unsigned short* __restrict__ A,  // Xhat bf16 [16384][2048]
    const unsigned short* __restrict__ B,  // Wout bf16 [2048][2048] (row j = out col)
    const float* __restrict__ hidden, const float* __restrict__ gate,
    float* __restrict__ out) {
  __shared__ unsigned short As[2][128 * 64];
  __shared__ unsigned short Bs[2][128 * 64];
  const int tid = threadIdx.x;
  const int bm = blockIdx.x >> 4, bn = blockIdx.x & 15;
  const int row0 = bm * 128, col0 = bn * 128;
  const int wave = tid >> 6, lane = tid & 63;
  const int wr = wave >> 1, wc = wave & 1;
  const int fl = lane & 15, fk = lane >> 4;
  const int srow = tid >> 3, scol = (tid & 7) * 8;

  f32x4 acc[4][4];
#pragma unroll
  for (int m = 0; m < 4; ++m)
#pragma unroll
    for (int n = 0; n < 4; ++n) acc[m][n] = (f32x4){0.f, 0.f, 0.f, 0.f};

  auto stage = [&](int buf, int kt) {
    const int k0 = kt * 64;
#pragma unroll
    for (int p = 0; p < 4; ++p) {
      int r = srow + p * 32;
      lds_load16(&As[buf][r * 64 + scol], A + (size_t)(row0 + r) * D_ + k0 + scol);
      lds_load16(&Bs[buf][r * 64 + scol], B + (size_t)(col0 + r) * D_ + k0 + scol);
    }
  };

  stage(0, 0);
  for (int kt = 0; kt < 32; ++kt) {
    __syncthreads();  // stage(kt) complete (drains vmcnt)
    if (kt + 1 < 32) stage((kt + 1) & 1, kt + 1);
    const int cb = kt & 1;
#pragma unroll
    for (int kkk = 0; kkk < 2; ++kkk) {
      bf16x8 af[4], bfr[4];
#pragma unroll
      for (int m = 0; m < 4; ++m)
        af[m] = *(const bf16x8*)&As[cb][(wr * 64 + m * 16 + fl) * 64 + kkk * 32 + fk * 8];
#pragma unroll
      for (int n = 0; n < 4; ++n)
        bfr[n] = *(const bf16x8*)&Bs[cb][(wc * 64 + n * 16 + fl) * 64 + kkk * 32 + fk * 8];
#pragma unroll
      for (int m = 0; m < 4; ++m)
#pragma unroll
        for (int n = 0; n < 4; ++n)
          acc[m][n] = __builtin_amdgcn_mfma_f32_16x16x32_bf16(af[m], bfr[n], acc[m][n], 0, 0, 0);
    }
  }
  float g = 1.f / (1.f + __expf(-gate[0]));
#pragma unroll
  for (int m = 0; m < 4; ++m)
#pragma unroll
    for (int n = 0; n < 4; ++n)
#pragma unroll
      for (int r = 0; r < 4; ++r) {
        int row = row0 + wr * 64 + m * 16 + fk * 4 + r;
        int col = col0 + wc * 64 + n * 16 + fl;
        size_t idx = (size_t)row * D_ + col;
        out[idx] = hidden[idx] + g * acc[m][n][r];
      }
}

extern "C" void kernel_launch(void* const* d_in, const int* in_sizes, int n_in,
                              void* d_out, int out_size, void* d_ws, size_t ws_size,
                              hipStream_t stream) {
  const float* hidden = (const float*)d_in[0];
  const float* mem    = (const float*)d_in[1];
  const float* wrq = (const float*)d_in[2];
  const float* wrk = (const float*)d_in[3];
  const float* wrv = (const float*)d_in[4];
  const float* wro = (const float*)d_in[5];
  const float* wwq = (const float*)d_in[6];
  const float* wwk = (const float*)d_in[7];
  const float* wwv = (const float*)d_in[8];
  const float* gamma = (const float*)d_in[9];
  const float* beta  = (const float*)d_in[10];
  const float* gate  = (const float*)d_in[11];
  const float* wgate = (const float*)d_in[12];
  float* out = (float*)d_out;

  char* ws = (char*)d_ws;
  float* kbuf  = (float*)(ws);
  float* vbuf  = (float*)(ws + (64 << 10));
  float* wqbuf = (float*)(ws + (128 << 10));
  float* PRT   = (float*)(ws + (192 << 10));           // 80*2048*4 = 640KB
  float* tbuf  = (float*)(ws + (832 << 10));           // 64KB
  float* Zpart = (float*)(ws + (896 << 10));           // 8KB
  float* upart = (float*)(ws + (1ull << 20));          // 16MB
  unsigned short* woutb = (unsigned short*)(ws + (17ull << 20));  // 8MB
  unsigned short* Xhat  = (unsigned short*)(ws + (25ull << 20));  // 64MB -> 89MB total

  hipMemsetAsync(PRT, 0, 80 * 2048 * sizeof(float), stream);
  k_cvt<<<(2048 * 2048 / 4 + 255) / 256, 256, 0, stream>>>(wro, woutb, 2048 * 2048 / 4);
  k_kvwq<<<1536, 256, 0, stream>>>(mem, wrk, wrv, wwq, kbuf, vbuf, wqbuf);
  k_pr<<<128, 256, 0, stream>>>(wrq, wwk, kbuf, wqbuf, PRT);
  k_main<<<256, 256, 0, stream>>>(hidden, PRT, vbuf, gamma, beta, Xhat, upart, Zpart);
  k_ured<<<64, 256, 0, stream>>>(upart, Zpart, tbuf);
  k_newmem<<<512, 256, 0, stream>>>(tbuf, wwv, mem, wgate, out + (size_t)N_ * D_);
  k_gemm<<<2048, 256, 0, stream>>>(Xhat, woutb, hidden, gate, out);
}